// Round 1
// baseline (427.907 us; speedup 1.0000x reference)
//
#include <hip/hip_runtime.h>
#include <hip/hip_bf16.h>

#define APPR_WEIGHT 0.15f
#define D_FEAT 64

// out = x  (vectorized copy, float4)
__global__ void appr_copy_kernel(const float4* __restrict__ x,
                                 float4* __restrict__ out, int n4) {
    int i = blockIdx.x * blockDim.x + threadIdx.x;
    if (i < n4) out[i] = x[i];
}

// out[dst[e]][f] += WEIGHT * x[src[e]][f], one thread per (edge, feature).
// Each 64-lane wave handles exactly one edge: lane f reads x[src*64+f]
// (coalesced 256B) and atomically adds to out[dst*64+f] (coalesced 256B).
__global__ void appr_scatter_kernel(const float* __restrict__ x,
                                    const int* __restrict__ src,
                                    const int* __restrict__ dst,
                                    float* __restrict__ out,
                                    int n_edges) {
    long long idx = (long long)blockIdx.x * blockDim.x + threadIdx.x;
    long long total = (long long)n_edges * D_FEAT;
    if (idx >= total) return;
    int e = (int)(idx >> 6);
    int f = (int)(idx & 63);
    int s = src[e];
    int d = dst[e];
    float v = APPR_WEIGHT * x[(long long)s * D_FEAT + f];
    // HW fp32 atomic (global_atomic_add_f32), device scope.
    unsafeAtomicAdd(&out[(long long)d * D_FEAT + f], v);
}

extern "C" void kernel_launch(void* const* d_in, const int* in_sizes, int n_in,
                              void* d_out, int out_size, void* d_ws, size_t ws_size,
                              hipStream_t stream) {
    const float* x = (const float*)d_in[0];
    const int* edge_index = (const int*)d_in[1];   // [2, E] int32
    float* out = (float*)d_out;

    int n_nodes_x_feat = in_sizes[0];              // N * 64
    int n_edges = in_sizes[1] / 2;

    const int* src = edge_index;                   // row 0
    const int* dst = edge_index + n_edges;         // row 1

    // 1) out = x
    int n4 = n_nodes_x_feat / 4;
    int cb = 256;
    int cg = (n4 + cb - 1) / cb;
    appr_copy_kernel<<<cg, cb, 0, stream>>>((const float4*)x, (float4*)out, n4);

    // 2) scatter-add
    long long total = (long long)n_edges * D_FEAT;
    int sb = 256;
    long long sg = (total + sb - 1) / sb;
    appr_scatter_kernel<<<(int)sg, sb, 0, stream>>>(x, src, dst, out, n_edges);
}